// Round 1
// 1024.010 us; speedup vs baseline: 1.0037x; 1.0037x over previous
//
#include <hip/hip_runtime.h>

// ---------------------------------------------------------------------------
// SClusterFormer block for MI355X (gfx950).
// Round 1: GEMM ladder step — global_load_lds width-16 staging + XOR chunk
// swizzle (conflict-free ds_read_b128) + fc2 retile for occupancy.
//   - bf16 MFMA (v_mfma_f32_16x16x32_bf16) for all GEMMs (f/v, proj, fc1, fc2)
//   - fp32 for LN, pooling, cosine-sim, argmax, aggregation
// ---------------------------------------------------------------------------

typedef __attribute__((ext_vector_type(8))) short short8;
typedef __attribute__((ext_vector_type(4))) short short4v;
typedef __attribute__((ext_vector_type(4))) float floatx4;

// float -> bf16 bits, round-to-nearest-even (inputs finite)
static __device__ __forceinline__ short f2bf(float f) {
  union { float f; unsigned u; } a; a.f = f;
  unsigned r = a.u + 0x7fffu + ((a.u >> 16) & 1u);
  return (short)(r >> 16);
}

// async global->LDS, 16 bytes per lane. LDS dest must be wave-uniform base +
// lane*16 (our staging index is lane-contiguous, so this holds).
static __device__ __forceinline__ void gload_lds16(const short* g, short* l) {
  __builtin_amdgcn_global_load_lds(
      (const __attribute__((address_space(1))) void*)g,
      (__attribute__((address_space(3))) void*)l, 16, 0, 0);
}

// ---------------------------------------------------------------------------
// f32 -> bf16 weight conversion (elementwise, float4 per thread)
__global__ __launch_bounds__(256) void cvt_f32_bf16(
    const float* __restrict__ in, short* __restrict__ out, int n4)
{
  int i = blockIdx.x * 256 + threadIdx.x;
  if (i >= n4) return;
  float4 v = reinterpret_cast<const float4*>(in)[i];
  short4v o;
  o[0] = f2bf(v.x); o[1] = f2bf(v.y); o[2] = f2bf(v.z); o[3] = f2bf(v.w);
  reinterpret_cast<short4v*>(out)[i] = o;
}

// ---------------------------------------------------------------------------
// LayerNorm over D=512, one wave per row, bf16 output.
__global__ __launch_bounds__(256) void ln_kernel(
    const float* __restrict__ x, const float* __restrict__ g,
    const float* __restrict__ b, short* __restrict__ out)
{
  const int wave = threadIdx.x >> 6, lane = threadIdx.x & 63;
  const size_t row = (size_t)blockIdx.x * 4 + wave;
  const float* xr = x + row * 512;
  const int c = lane * 8;
  float4 v0 = *reinterpret_cast<const float4*>(xr + c);
  float4 v1 = *reinterpret_cast<const float4*>(xr + c + 4);
  float xs[8] = {v0.x, v0.y, v0.z, v0.w, v1.x, v1.y, v1.z, v1.w};
  float s = 0.f, q = 0.f;
#pragma unroll
  for (int k = 0; k < 8; ++k) { s += xs[k]; q += xs[k] * xs[k]; }
#pragma unroll
  for (int off = 32; off; off >>= 1) {
    s += __shfl_xor(s, off);
    q += __shfl_xor(q, off);
  }
  const float mean = s * (1.0f / 512.0f);
  const float var  = q * (1.0f / 512.0f) - mean * mean;
  const float rstd = rsqrtf(var + 1e-5f);
  short8 o;
#pragma unroll
  for (int k = 0; k < 8; ++k)
    o[k] = f2bf((xs[k] - mean) * rstd * g[c + k] + b[c + k]);
  *reinterpret_cast<short8*>(out + row * 512 + c) = o;
}

// ---------------------------------------------------------------------------
// GEMM: C[m,n] = epi( A[m,:] . W[n,:] + bias[n] )
//   A: bf16 [M,K] row-major, W: bf16 [N,K] row-major (i.e. B^T layout).
//   EPI 0: store f32      EPI 1: +resid, store f32      EPI 2: gelu, store bf16
// 4 waves/block; wave computes WM x WN via 16x16x32 bf16 MFMA.
// Staging: global_load_lds dwordx4, linear LDS dest, pre-swizzled global src;
// ds_read uses the same XOR -> conflict-free (slot = k ^ ((row>>1)&3)).
template<int BM, int BN, int WM, int WN, int EPI>
__global__ __launch_bounds__(256, 2) void gemm_bt(
    const short* __restrict__ A, const short* __restrict__ W,
    const float* __restrict__ bias, const float* __restrict__ resid,
    float* __restrict__ Cf, short* __restrict__ Cb,
    const int N, const int K)
{
  constexpr int BK = 32;                 // 4 chunks of 8 bf16 per row
  __shared__ short Al[BM * BK];
  __shared__ short Wl[BN * BK];
  const int tid  = threadIdx.x;
  const int wave = tid >> 6;
  const int lane = tid & 63;
  constexpr int WCOLS = BN / WN;
  const int wm = (wave / WCOLS) * WM;
  const int wn = (wave % WCOLS) * WN;
  constexpr int MI = WM / 16, NJ = WN / 16;
  const int row0 = blockIdx.x * BM;
  const int col0 = blockIdx.y * BN;
  const int r  = lane & 15;          // MFMA row (A) / col (B) / col (C)
  const int kc = lane >> 4;          // MFMA k-chunk index (0..3)

  floatx4 acc[MI][NJ];
#pragma unroll
  for (int i = 0; i < MI; ++i)
#pragma unroll
    for (int j = 0; j < NJ; ++j)
      acc[i][j] = (floatx4){0.f, 0.f, 0.f, 0.f};

  const short* Ab = A + (size_t)row0 * K;
  const short* Wb = W + (size_t)col0 * K;

  // staging descriptors (constant across K-steps): chunk cc -> row rr, slot sl,
  // global k-chunk co = sl ^ ((rr>>1)&3)
  for (int k0 = 0; k0 < K; k0 += BK) {
#pragma unroll
    for (int u = 0; u < BM / 64; ++u) {
      const int cc = u * 256 + tid;
      const int rr = cc >> 2, sl = cc & 3;
      const int co = sl ^ ((rr >> 1) & 3);
      gload_lds16(Ab + (size_t)rr * K + k0 + co * 8, &Al[cc * 8]);
    }
#pragma unroll
    for (int u = 0; u < BN / 64; ++u) {
      const int cc = u * 256 + tid;
      const int rr = cc >> 2, sl = cc & 3;
      const int co = sl ^ ((rr >> 1) & 3);
      gload_lds16(Wb + (size_t)rr * K + k0 + co * 8, &Wl[cc * 8]);
    }
    __syncthreads();   // drains vmcnt(0): loads have landed in LDS
    short8 af[MI], wfr[NJ];
#pragma unroll
    for (int i = 0; i < MI; ++i) {
      const int rt = wm + 16 * i + r;
      af[i] = *reinterpret_cast<const short8*>(
          &Al[rt * BK + ((kc ^ ((rt >> 1) & 3)) << 3)]);
    }
#pragma unroll
    for (int j = 0; j < NJ; ++j) {
      const int rt = wn + 16 * j + r;
      wfr[j] = *reinterpret_cast<const short8*>(
          &Wl[rt * BK + ((kc ^ ((rt >> 1) & 3)) << 3)]);
    }
#pragma unroll
    for (int i = 0; i < MI; ++i)
#pragma unroll
      for (int j = 0; j < NJ; ++j)
        acc[i][j] = __builtin_amdgcn_mfma_f32_16x16x32_bf16(
            af[i], wfr[j], acc[i][j], 0, 0, 0);
    __syncthreads();
  }

  // epilogue: C/D layout col=lane&15, row=(lane>>4)*4+reg
#pragma unroll
  for (int i = 0; i < MI; ++i) {
#pragma unroll
    for (int j = 0; j < NJ; ++j) {
      const int col = col0 + wn + 16 * j + r;
      const float bv = bias[col];
#pragma unroll
      for (int t = 0; t < 4; ++t) {
        const int rowi = row0 + wm + 16 * i + (lane >> 4) * 4 + t;
        const size_t offo = (size_t)rowi * N + col;
        float v = acc[i][j][t] + bv;
        if (EPI == 0) {
          Cf[offo] = v;
        } else if (EPI == 1) {
          Cf[offo] = v + resid[offo];
        } else {
          v = 0.5f * v * (1.0f + erff(v * 0.70710678118654752f));
          Cb[offo] = f2bf(v);
        }
      }
    }
  }
}

// ---------------------------------------------------------------------------
// AdaptiveAvgPool 32x32 -> 4x4 per (b,h); writes normalized centers (cn) and
// pooled values (vcent). One block per bh, 384 threads = (m, c).
__global__ __launch_bounds__(384) void pool_kernel(
    const float* __restrict__ feat, const float* __restrict__ val,
    float* __restrict__ cn, float* __restrict__ vcent)
{
  const int bh = blockIdx.x;
  const int b = bh >> 3, h = bh & 7;
  const int t = threadIdx.x;        // 0..383
  const int m = t / 24, c = t % 24;
  const int cy = m >> 2, cx = m & 3;
  const size_t base = (size_t)b * 1024 * 192 + h * 24 + c;
  float sf = 0.f, sv = 0.f;
  for (int dy = 0; dy < 8; ++dy) {
    const int ny = (cy * 8 + dy) * 32 + cx * 8;
    for (int dx = 0; dx < 8; ++dx) {
      const size_t off = base + (size_t)(ny + dx) * 192;
      sf += feat[off];
      sv += val[off];
    }
  }
  sf *= (1.0f / 64.0f); sv *= (1.0f / 64.0f);
  __shared__ float cent[16][24];
  cent[m][c] = sf;
  vcent[(size_t)bh * 384 + t] = sv;
  __syncthreads();
  float nrm = 0.f;
#pragma unroll
  for (int k = 0; k < 24; ++k) nrm += cent[m][k] * cent[m][k];
  nrm = fmaxf(sqrtf(nrm), 1e-12f);
  cn[(size_t)bh * 384 + t] = sf / nrm;
}

// ---------------------------------------------------------------------------
// Per token: cosine sim vs 16 centers, leaky-relu, top-1 -> (value, index).
__global__ __launch_bounds__(256) void sim_kernel(
    const float* __restrict__ feat, const float* __restrict__ cn,
    const float* __restrict__ alpha_p, const float* __restrict__ beta_p,
    float* __restrict__ sval, int* __restrict__ sidx)
{
  const int bh = blockIdx.y;
  const int b = bh >> 3, h = bh & 7;
  __shared__ float cs[384];
  for (int i = threadIdx.x; i < 384; i += 256) cs[i] = cn[(size_t)bh * 384 + i];
  __syncthreads();
  const int n = blockIdx.x * 256 + threadIdx.x;
  const float* f = feat + (size_t)(b * 1024 + n) * 192 + h * 24;
  float v[24];
#pragma unroll
  for (int k = 0; k < 24; k += 4) {
    float4 t4 = *reinterpret_cast<const float4*>(f + k);
    v[k] = t4.x; v[k + 1] = t4.y; v[k + 2] = t4.z; v[k + 3] = t4.w;
  }
  float q = 0.f;
#pragma unroll
  for (int k = 0; k < 24; ++k) q += v[k] * v[k];
  const float inv = 1.0f / fmaxf(sqrtf(q), 1e-12f);
  const float alpha = alpha_p[0], beta = beta_p[0];
  float best = -3.4e38f; int bi = 0;
#pragma unroll
  for (int m = 0; m < 16; ++m) {
    float d = 0.f;
#pragma unroll
    for (int k = 0; k < 24; ++k) d += cs[m * 24 + k] * v[k];
    float s = beta + alpha * (d * inv);
    s = (s < 0.f) ? 0.2f * s : s;            // LeakyReLU(0.2)
    if (s > best) { best = s; bi = m; }      // strict > == first-max (jnp.argmax)
  }
  sval[(size_t)bh * 1024 + n] = best;
  sidx[(size_t)bh * 1024 + n] = bi;
}

// ---------------------------------------------------------------------------
// agg[bh,m,:] = (sum_{n: idx=m} s_n * vh[n,:] + vcent[m,:]) / (count_m + 1)
__global__ __launch_bounds__(256) void agg_kernel(
    const float* __restrict__ val, const float* __restrict__ vcent,
    const float* __restrict__ sval, const int* __restrict__ sidx,
    float* __restrict__ agg)
{
  const int bh = blockIdx.x;
  const int b = bh >> 3, h = bh & 7;
  __shared__ float acc[384];
  __shared__ float cnt[16];
  for (int i = threadIdx.x; i < 384; i += 256) acc[i] = 0.f;
  if (threadIdx.x < 16) cnt[threadIdx.x] = 0.f;
  __syncthreads();
  for (int n = threadIdx.x; n < 1024; n += 256) {
    const float s = sval[(size_t)bh * 1024 + n];
    const int m = sidx[(size_t)bh * 1024 + n];
    atomicAdd(&cnt[m], 1.0f);
    const float* vv = val + (size_t)(b * 1024 + n) * 192 + h * 24;
#pragma unroll
    for (int k = 0; k < 24; ++k) atomicAdd(&acc[m * 24 + k], s * vv[k]);
  }
  __syncthreads();
  for (int i = threadIdx.x; i < 384; i += 256) {
    const int m = i / 24;
    agg[(size_t)bh * 384 + i] = (acc[i] + vcent[(size_t)bh * 384 + i]) / (cnt[m] + 1.0f);
  }
}

// ---------------------------------------------------------------------------
// o[b,n,h*24+c] = s_n * agg[bh, idx_n, c]   (bf16 out, thread per (b,n,h))
__global__ __launch_bounds__(256) void dispatch_kernel(
    const float* __restrict__ sval, const int* __restrict__ sidx,
    const float* __restrict__ agg, short* __restrict__ o)
{
  const int g = blockIdx.x * 256 + threadIdx.x;      // b*8192 + n*8 + h
  const int h = g & 7, n = (g >> 3) & 1023, b = g >> 13;
  const int bh = b * 8 + h;
  const float s = sval[(size_t)bh * 1024 + n];
  const int m = sidx[(size_t)bh * 1024 + n];
  const float* a = agg + (size_t)bh * 384 + m * 24;
  short* op = o + ((size_t)(b * 1024 + n)) * 192 + h * 24;
  short8 pack[3];
#pragma unroll
  for (int k = 0; k < 24; ++k) pack[k >> 3][k & 7] = f2bf(s * a[k]);
  short8* dst = reinterpret_cast<short8*>(op);
  dst[0] = pack[0]; dst[1] = pack[1]; dst[2] = pack[2];
}

// ---------------------------------------------------------------------------
extern "C" void kernel_launch(void* const* d_in, const int* in_sizes, int n_in,
                              void* d_out, int out_size, void* d_ws, size_t ws_size,
                              hipStream_t stream)
{
  const float* x      = (const float*)d_in[0];
  const float* ln1_g  = (const float*)d_in[1];
  const float* ln1_b  = (const float*)d_in[2];
  const float* f_w    = (const float*)d_in[3];
  const float* f_b    = (const float*)d_in[4];
  const float* v_w    = (const float*)d_in[5];
  const float* v_b    = (const float*)d_in[6];
  const float* alpha  = (const float*)d_in[7];
  const float* beta   = (const float*)d_in[8];
  const float* proj_w = (const float*)d_in[9];
  const float* proj_b = (const float*)d_in[10];
  const float* ln2_g  = (const float*)d_in[11];
  const float* ln2_b  = (const float*)d_in[12];
  const float* fc1_w  = (const float*)d_in[13];
  const float* fc1_b  = (const float*)d_in[14];
  const float* fc2_w  = (const float*)d_in[15];
  const float* fc2_b  = (const float*)d_in[16];
  float* out = (float*)d_out;

  char* ws = (char*)d_ws;
  size_t off = 0;
  auto alloc = [&](size_t bytes) -> char* {
    char* p = ws + off;
    off = (off + bytes + 255) & ~(size_t)255;
    return p;
  };
  // total ~339 MB; h1 aliases xn (dead after f/v GEMMs), h aliases feat+val
  short* xn   = (short*)alloc(67108864);    // LN1 out, bf16 [65536,512]
  float* feat = (float*)alloc(50331648);    // f32 [65536,192]
  float* val  = (float*)alloc(50331648);    // f32 [65536,192]
  short* o    = (short*)alloc(25165824);    // bf16 [65536,192]
  float* x1   = (float*)alloc(134217728);   // f32 [65536,512] residual stream
  short* wf   = (short*)alloc(196608);
  short* wv   = (short*)alloc(196608);
  short* wp   = (short*)alloc(196608);
  short* w1   = (short*)alloc(2097152);
  short* w2   = (short*)alloc(2097152);
  float* cnb  = (float*)alloc(786432);      // [512,16,24]
  float* vcb  = (float*)alloc(786432);
  float* agb  = (float*)alloc(786432);
  float* svb  = (float*)alloc(2097152);     // [512,1024]
  int*   sib  = (int*)  alloc(2097152);
  short* h  = (short*)feat;                 // LN2 out bf16 [65536,512] (aliases feat+val)
  short* h1 = xn;                           // fc1 out bf16 [16384,2048] chunk (aliases xn)

  // weight conversions
  cvt_f32_bf16<<<96,   256, 0, stream>>>(f_w,    wf, 24576);
  cvt_f32_bf16<<<96,   256, 0, stream>>>(v_w,    wv, 24576);
  cvt_f32_bf16<<<96,   256, 0, stream>>>(proj_w, wp, 24576);
  cvt_f32_bf16<<<1024, 256, 0, stream>>>(fc1_w,  w1, 262144);
  cvt_f32_bf16<<<1024, 256, 0, stream>>>(fc2_w,  w2, 262144);

  // 1. xn = LN1(x)
  ln_kernel<<<16384, 256, 0, stream>>>(x, ln1_g, ln1_b, xn);

  // 2. feat/val = xn @ {f,v}_w^T + bias    [65536,192] f32
  gemm_bt<128, 64, 64, 32, 0><<<dim3(512, 3), 256, 0, stream>>>(
      xn, wf, f_b, nullptr, feat, nullptr, 192, 512);
  gemm_bt<128, 64, 64, 32, 0><<<dim3(512, 3), 256, 0, stream>>>(
      xn, wv, v_b, nullptr, val, nullptr, 192, 512);

  // 3. cluster centers + normalize
  pool_kernel<<<512, 384, 0, stream>>>(feat, val, cnb, vcb);
  // 4. sim + leaky + top-1
  sim_kernel<<<dim3(4, 512), 256, 0, stream>>>(feat, cnb, alpha, beta, svb, sib);
  // 5. aggregate into centers
  agg_kernel<<<512, 256, 0, stream>>>(val, vcb, svb, sib, agb);
  // 6. dispatch back to tokens (bf16)
  dispatch_kernel<<<2048, 256, 0, stream>>>(svb, sib, agb, o);

  // 7. x1 = x + o @ proj_w^T + proj_b
  gemm_bt<128, 128, 64, 64, 1><<<dim3(512, 4), 256, 0, stream>>>(
      o, wp, proj_b, x, x1, nullptr, 512, 192);

  // 8. h = LN2(x1)  (bf16)
  ln_kernel<<<16384, 256, 0, stream>>>(x1, ln2_g, ln2_b, h);

  // 9/10. MLP, 4 row-chunks of 16384 to bound workspace
  //   fc2 at BN=64 -> grid 128x8 = 1024 blocks (4 blocks/CU vs 2 before)
  for (int c = 0; c < 4; ++c) {
    const short* hA = h + (size_t)c * 16384 * 512;
    gemm_bt<128, 128, 64, 64, 2><<<dim3(128, 16), 256, 0, stream>>>(
        hA, w1, fc1_b, nullptr, nullptr, h1, 2048, 512);
    gemm_bt<128, 64, 64, 32, 1><<<dim3(128, 8), 256, 0, stream>>>(
        h1, w2, fc2_b, x1 + (size_t)c * 16384 * 512,
        out + (size_t)c * 16384 * 512, nullptr, 512, 2048);
  }
  (void)in_sizes; (void)n_in; (void)out_size; (void)ws_size;
}

// Round 3
// 1002.303 us; speedup vs baseline: 1.0254x; 1.0217x over previous
//
#include <hip/hip_runtime.h>

// ---------------------------------------------------------------------------
// SClusterFormer block for MI355X (gfx950).
// Round 3: round-2 pipeline with round-1's known-good memory footprint.
//   - 2-phase double-buffered LDS pipeline (prefetch next K-tile via
//     global_load_lds BEFORE compute; single barrier per K-step)
//   - workspace layout reverted to round-1 aliasing (~338 MB total):
//     h aliases feat+val, h1 aliases xn, MLP in 4 row-chunks
//   - fc2 retiled 128x64 (wave 64x32) -> 1024 blocks/chunk, 16 waves/CU
//   - XOR chunk swizzle kept (conflict-free ds_read_b128)
// ---------------------------------------------------------------------------

typedef __attribute__((ext_vector_type(8))) short short8;
typedef __attribute__((ext_vector_type(4))) short short4v;
typedef __attribute__((ext_vector_type(4))) float floatx4;

// float -> bf16 bits, round-to-nearest-even (inputs finite)
static __device__ __forceinline__ short f2bf(float f) {
  union { float f; unsigned u; } a; a.f = f;
  unsigned r = a.u + 0x7fffu + ((a.u >> 16) & 1u);
  return (short)(r >> 16);
}

// async global->LDS, 16 bytes per lane. LDS dest must be wave-uniform base +
// lane*16 (our staging index is lane-contiguous per wave, so this holds).
static __device__ __forceinline__ void gload_lds16(const short* g, short* l) {
  __builtin_amdgcn_global_load_lds(
      (const __attribute__((address_space(1))) void*)g,
      (__attribute__((address_space(3))) void*)l, 16, 0, 0);
}

// ---------------------------------------------------------------------------
// f32 -> bf16 weight conversion (elementwise, float4 per thread)
__global__ __launch_bounds__(256) void cvt_f32_bf16(
    const float* __restrict__ in, short* __restrict__ out, int n4)
{
  int i = blockIdx.x * 256 + threadIdx.x;
  if (i >= n4) return;
  float4 v = reinterpret_cast<const float4*>(in)[i];
  short4v o;
  o[0] = f2bf(v.x); o[1] = f2bf(v.y); o[2] = f2bf(v.z); o[3] = f2bf(v.w);
  reinterpret_cast<short4v*>(out)[i] = o;
}

// ---------------------------------------------------------------------------
// LayerNorm over D=512, one wave per row, bf16 output.
__global__ __launch_bounds__(256) void ln_kernel(
    const float* __restrict__ x, const float* __restrict__ g,
    const float* __restrict__ b, short* __restrict__ out)
{
  const int wave = threadIdx.x >> 6, lane = threadIdx.x & 63;
  const size_t row = (size_t)blockIdx.x * 4 + wave;
  const float* xr = x + row * 512;
  const int c = lane * 8;
  float4 v0 = *reinterpret_cast<const float4*>(xr + c);
  float4 v1 = *reinterpret_cast<const float4*>(xr + c + 4);
  float xs[8] = {v0.x, v0.y, v0.z, v0.w, v1.x, v1.y, v1.z, v1.w};
  float s = 0.f, q = 0.f;
#pragma unroll
  for (int k = 0; k < 8; ++k) { s += xs[k]; q += xs[k] * xs[k]; }
#pragma unroll
  for (int off = 32; off; off >>= 1) {
    s += __shfl_xor(s, off);
    q += __shfl_xor(q, off);
  }
  const float mean = s * (1.0f / 512.0f);
  const float var  = q * (1.0f / 512.0f) - mean * mean;
  const float rstd = rsqrtf(var + 1e-5f);
  short8 o;
#pragma unroll
  for (int k = 0; k < 8; ++k)
    o[k] = f2bf((xs[k] - mean) * rstd * g[c + k] + b[c + k]);
  *reinterpret_cast<short8*>(out + row * 512 + c) = o;
}

// ---------------------------------------------------------------------------
// GEMM: C[m,n] = epi( A[m,:] . W[n,:] + bias[n] )
//   A: bf16 [M,K] row-major, W: bf16 [N,K] row-major (i.e. B^T layout).
//   EPI 0: store f32      EPI 1: +resid, store f32      EPI 2: gelu, store bf16
// 256 threads (4 waves); wave computes WM x WN via 16x16x32 bf16 MFMA.
// 2-phase pipeline: double-buffered LDS; prefetch next K-tile (global_load_lds
// dwordx4, pre-swizzled global src, linear LDS dest) before ds_read+MFMA of
// the current tile; one __syncthreads per K-step (drains vmcnt+lgkm).
template<int BM, int BN, int WM, int WN, int EPI>
__global__ __launch_bounds__(256, 2) void gemm_bt(
    const short* __restrict__ A, const short* __restrict__ W,
    const float* __restrict__ bias, const float* __restrict__ resid,
    float* __restrict__ Cf, short* __restrict__ Cb,
    const int N, const int K)
{
  constexpr int BK = 32;                 // 4 chunks of 8 bf16 per row
  constexpr int T  = 256;
  constexpr int AC = (BM * BK / 8) / T;  // A gload16 per thread per tile
  constexpr int WC = (BN * BK / 8) / T;  // W gload16 per thread per tile
  __shared__ short Al[2][BM * BK];
  __shared__ short Wl[2][BN * BK];
  const int tid  = threadIdx.x;
  const int wave = tid >> 6;
  const int lane = tid & 63;
  constexpr int WCOLS = BN / WN;
  const int wm = (wave / WCOLS) * WM;
  const int wn = (wave % WCOLS) * WN;
  constexpr int MI = WM / 16, NJ = WN / 16;
  const int row0 = blockIdx.x * BM;
  const int col0 = blockIdx.y * BN;
  const int r  = lane & 15;          // MFMA row (A) / col (B) / col (C)
  const int kc = lane >> 4;          // MFMA k-chunk index (0..3)

  floatx4 acc[MI][NJ];
#pragma unroll
  for (int i = 0; i < MI; ++i)
#pragma unroll
    for (int j = 0; j < NJ; ++j)
      acc[i][j] = (floatx4){0.f, 0.f, 0.f, 0.f};

  const short* Ab = A + (size_t)row0 * K;
  const short* Wb = W + (size_t)col0 * K;

  // hoisted staging descriptors: chunk cc -> row rr, slot sl, swizzled global
  // k-chunk co = sl ^ ((rr>>1)&3); LDS dest linear at cc*16B
  const short* aSrc[AC]; int aDst[AC];
#pragma unroll
  for (int u = 0; u < AC; ++u) {
    const int cc = u * T + tid;
    const int rr = cc >> 2, sl = cc & 3;
    const int co = sl ^ ((rr >> 1) & 3);
    aSrc[u] = Ab + (size_t)rr * K + co * 8;
    aDst[u] = cc * 8;
  }
  const short* wSrc[WC]; int wDst[WC];
#pragma unroll
  for (int u = 0; u < WC; ++u) {
    const int cc = u * T + tid;
    const int rr = cc >> 2, sl = cc & 3;
    const int co = sl ^ ((rr >> 1) & 3);
    wSrc[u] = Wb + (size_t)rr * K + co * 8;
    wDst[u] = cc * 8;
  }
  // hoisted ds_read offsets (shorts), same XOR as staging
  int aOff[MI], wOff[NJ];
#pragma unroll
  for (int i = 0; i < MI; ++i) {
    const int rt = wm + 16 * i + r;
    aOff[i] = rt * BK + ((kc ^ ((rt >> 1) & 3)) << 3);
  }
#pragma unroll
  for (int j = 0; j < NJ; ++j) {
    const int rt = wn + 16 * j + r;
    wOff[j] = rt * BK + ((kc ^ ((rt >> 1) & 3)) << 3);
  }

  auto stage = [&](int buf, int k0) {
#pragma unroll
    for (int u = 0; u < AC; ++u) gload_lds16(aSrc[u] + k0, &Al[buf][aDst[u]]);
#pragma unroll
    for (int u = 0; u < WC; ++u) gload_lds16(wSrc[u] + k0, &Wl[buf][wDst[u]]);
  };

  stage(0, 0);
  __syncthreads();                       // vmcnt(0) drain + barrier
  int cur = 0;
  for (int k0 = BK; k0 <= K; k0 += BK) { // k0 = NEXT tile base
    if (k0 < K) stage(cur ^ 1, k0);      // issue prefetch first
    short8 af[MI], wfr[NJ];
#pragma unroll
    for (int i = 0; i < MI; ++i)
      af[i] = *reinterpret_cast<const short8*>(&Al[cur][aOff[i]]);
#pragma unroll
    for (int j = 0; j < NJ; ++j)
      wfr[j] = *reinterpret_cast<const short8*>(&Wl[cur][wOff[j]]);
#pragma unroll
    for (int i = 0; i < MI; ++i)
#pragma unroll
      for (int j = 0; j < NJ; ++j)
        acc[i][j] = __builtin_amdgcn_mfma_f32_16x16x32_bf16(
            af[i], wfr[j], acc[i][j], 0, 0, 0);
    __syncthreads();                     // prefetch landed; buffers swappable
    cur ^= 1;
  }

  // epilogue: C/D layout col=lane&15, row=(lane>>4)*4+reg
#pragma unroll
  for (int i = 0; i < MI; ++i) {
#pragma unroll
    for (int j = 0; j < NJ; ++j) {
      const int col = col0 + wn + 16 * j + r;
      const float bv = bias[col];
#pragma unroll
      for (int t = 0; t < 4; ++t) {
        const int rowi = row0 + wm + 16 * i + (lane >> 4) * 4 + t;
        const size_t offo = (size_t)rowi * N + col;
        float v = acc[i][j][t] + bv;
        if (EPI == 0) {
          Cf[offo] = v;
        } else if (EPI == 1) {
          Cf[offo] = v + resid[offo];
        } else {
          v = 0.5f * v * (1.0f + erff(v * 0.70710678118654752f));
          Cb[offo] = f2bf(v);
        }
      }
    }
  }
}

// ---------------------------------------------------------------------------
// AdaptiveAvgPool 32x32 -> 4x4 per (b,h); writes normalized centers (cn) and
// pooled values (vcent). One block per bh, 384 threads = (m, c).
__global__ __launch_bounds__(384) void pool_kernel(
    const float* __restrict__ feat, const float* __restrict__ val,
    float* __restrict__ cn, float* __restrict__ vcent)
{
  const int bh = blockIdx.x;
  const int b = bh >> 3, h = bh & 7;
  const int t = threadIdx.x;        // 0..383
  const int m = t / 24, c = t % 24;
  const int cy = m >> 2, cx = m & 3;
  const size_t base = (size_t)b * 1024 * 192 + h * 24 + c;
  float sf = 0.f, sv = 0.f;
  for (int dy = 0; dy < 8; ++dy) {
    const int ny = (cy * 8 + dy) * 32 + cx * 8;
    for (int dx = 0; dx < 8; ++dx) {
      const size_t off = base + (size_t)(ny + dx) * 192;
      sf += feat[off];
      sv += val[off];
    }
  }
  sf *= (1.0f / 64.0f); sv *= (1.0f / 64.0f);
  __shared__ float cent[16][24];
  cent[m][c] = sf;
  vcent[(size_t)bh * 384 + t] = sv;
  __syncthreads();
  float nrm = 0.f;
#pragma unroll
  for (int k = 0; k < 24; ++k) nrm += cent[m][k] * cent[m][k];
  nrm = fmaxf(sqrtf(nrm), 1e-12f);
  cn[(size_t)bh * 384 + t] = sf / nrm;
}

// ---------------------------------------------------------------------------
// Per token: cosine sim vs 16 centers, leaky-relu, top-1 -> (value, index).
__global__ __launch_bounds__(256) void sim_kernel(
    const float* __restrict__ feat, const float* __restrict__ cn,
    const float* __restrict__ alpha_p, const float* __restrict__ beta_p,
    float* __restrict__ sval, int* __restrict__ sidx)
{
  const int bh = blockIdx.y;
  const int b = bh >> 3, h = bh & 7;
  __shared__ float cs[384];
  for (int i = threadIdx.x; i < 384; i += 256) cs[i] = cn[(size_t)bh * 384 + i];
  __syncthreads();
  const int n = blockIdx.x * 256 + threadIdx.x;
  const float* f = feat + (size_t)(b * 1024 + n) * 192 + h * 24;
  float v[24];
#pragma unroll
  for (int k = 0; k < 24; k += 4) {
    float4 t4 = *reinterpret_cast<const float4*>(f + k);
    v[k] = t4.x; v[k + 1] = t4.y; v[k + 2] = t4.z; v[k + 3] = t4.w;
  }
  float q = 0.f;
#pragma unroll
  for (int k = 0; k < 24; ++k) q += v[k] * v[k];
  const float inv = 1.0f / fmaxf(sqrtf(q), 1e-12f);
  const float alpha = alpha_p[0], beta = beta_p[0];
  float best = -3.4e38f; int bi = 0;
#pragma unroll
  for (int m = 0; m < 16; ++m) {
    float d = 0.f;
#pragma unroll
    for (int k = 0; k < 24; ++k) d += cs[m * 24 + k] * v[k];
    float s = beta + alpha * (d * inv);
    s = (s < 0.f) ? 0.2f * s : s;            // LeakyReLU(0.2)
    if (s > best) { best = s; bi = m; }      // strict > == first-max (jnp.argmax)
  }
  sval[(size_t)bh * 1024 + n] = best;
  sidx[(size_t)bh * 1024 + n] = bi;
}

// ---------------------------------------------------------------------------
// agg[bh,m,:] = (sum_{n: idx=m} s_n * vh[n,:] + vcent[m,:]) / (count_m + 1)
__global__ __launch_bounds__(256) void agg_kernel(
    const float* __restrict__ val, const float* __restrict__ vcent,
    const float* __restrict__ sval, const int* __restrict__ sidx,
    float* __restrict__ agg)
{
  const int bh = blockIdx.x;
  const int b = bh >> 3, h = bh & 7;
  __shared__ float acc[384];
  __shared__ float cnt[16];
  for (int i = threadIdx.x; i < 384; i += 256) acc[i] = 0.f;
  if (threadIdx.x < 16) cnt[threadIdx.x] = 0.f;
  __syncthreads();
  for (int n = threadIdx.x; n < 1024; n += 256) {
    const float s = sval[(size_t)bh * 1024 + n];
    const int m = sidx[(size_t)bh * 1024 + n];
    atomicAdd(&cnt[m], 1.0f);
    const float* vv = val + (size_t)(b * 1024 + n) * 192 + h * 24;
#pragma unroll
    for (int k = 0; k < 24; ++k) atomicAdd(&acc[m * 24 + k], s * vv[k]);
  }
  __syncthreads();
  for (int i = threadIdx.x; i < 384; i += 256) {
    const int m = i / 24;
    agg[(size_t)bh * 384 + i] = (acc[i] + vcent[(size_t)bh * 384 + i]) / (cnt[m] + 1.0f);
  }
}

// ---------------------------------------------------------------------------
// o[b,n,h*24+c] = s_n * agg[bh, idx_n, c]   (bf16 out, thread per (b,n,h))
__global__ __launch_bounds__(256) void dispatch_kernel(
    const float* __restrict__ sval, const int* __restrict__ sidx,
    const float* __restrict__ agg, short* __restrict__ o)
{
  const int g = blockIdx.x * 256 + threadIdx.x;      // b*8192 + n*8 + h
  const int h = g & 7, n = (g >> 3) & 1023, b = g >> 13;
  const int bh = b * 8 + h;
  const float s = sval[(size_t)bh * 1024 + n];
  const int m = sidx[(size_t)bh * 1024 + n];
  const float* a = agg + (size_t)bh * 384 + m * 24;
  short* op = o + ((size_t)(b * 1024 + n)) * 192 + h * 24;
  short8 pack[3];
#pragma unroll
  for (int k = 0; k < 24; ++k) pack[k >> 3][k & 7] = f2bf(s * a[k]);
  short8* dst = reinterpret_cast<short8*>(op);
  dst[0] = pack[0]; dst[1] = pack[1]; dst[2] = pack[2];
}

// ---------------------------------------------------------------------------
extern "C" void kernel_launch(void* const* d_in, const int* in_sizes, int n_in,
                              void* d_out, int out_size, void* d_ws, size_t ws_size,
                              hipStream_t stream)
{
  const float* x      = (const float*)d_in[0];
  const float* ln1_g  = (const float*)d_in[1];
  const float* ln1_b  = (const float*)d_in[2];
  const float* f_w    = (const float*)d_in[3];
  const float* f_b    = (const float*)d_in[4];
  const float* v_w    = (const float*)d_in[5];
  const float* v_b    = (const float*)d_in[6];
  const float* alpha  = (const float*)d_in[7];
  const float* beta   = (const float*)d_in[8];
  const float* proj_w = (const float*)d_in[9];
  const float* proj_b = (const float*)d_in[10];
  const float* ln2_g  = (const float*)d_in[11];
  const float* ln2_b  = (const float*)d_in[12];
  const float* fc1_w  = (const float*)d_in[13];
  const float* fc1_b  = (const float*)d_in[14];
  const float* fc2_w  = (const float*)d_in[15];
  const float* fc2_b  = (const float*)d_in[16];
  float* out = (float*)d_out;

  char* ws = (char*)d_ws;
  size_t off = 0;
  auto alloc = [&](size_t bytes) -> char* {
    char* p = ws + off;
    off = (off + bytes + 255) & ~(size_t)255;
    return p;
  };
  // total ~339 MB (round-1 proven); h1 aliases xn, h aliases feat+val
  short* xn   = (short*)alloc(67108864);    // LN1 out, bf16 [65536,512]
  float* feat = (float*)alloc(50331648);    // f32 [65536,192]
  float* val  = (float*)alloc(50331648);    // f32 [65536,192]
  short* o    = (short*)alloc(25165824);    // bf16 [65536,192]
  float* x1   = (float*)alloc(134217728);   // f32 [65536,512] residual stream
  short* wf   = (short*)alloc(196608);
  short* wv   = (short*)alloc(196608);
  short* wp   = (short*)alloc(196608);
  short* w1   = (short*)alloc(2097152);
  short* w2   = (short*)alloc(2097152);
  float* cnb  = (float*)alloc(786432);      // [512,16,24]
  float* vcb  = (float*)alloc(786432);
  float* agb  = (float*)alloc(786432);
  float* svb  = (float*)alloc(2097152);     // [512,1024]
  int*   sib  = (int*)  alloc(2097152);
  short* h  = (short*)feat;                 // LN2 out bf16 [65536,512] (aliases feat+val)
  short* h1 = xn;                           // fc1 out bf16 [16384,2048] chunk (aliases xn)

  // weight conversions
  cvt_f32_bf16<<<96,   256, 0, stream>>>(f_w,    wf, 24576);
  cvt_f32_bf16<<<96,   256, 0, stream>>>(v_w,    wv, 24576);
  cvt_f32_bf16<<<96,   256, 0, stream>>>(proj_w, wp, 24576);
  cvt_f32_bf16<<<1024, 256, 0, stream>>>(fc1_w,  w1, 262144);
  cvt_f32_bf16<<<1024, 256, 0, stream>>>(fc2_w,  w2, 262144);

  // 1. xn = LN1(x)
  ln_kernel<<<16384, 256, 0, stream>>>(x, ln1_g, ln1_b, xn);

  // 2. feat/val = xn @ {f,v}_w^T + bias    [65536,192] f32
  //    256x64 tiles: grid (256,3)=768 blocks, 16:8 MFMA:ds_read per wave
  gemm_bt<256, 64, 64, 64, 0><<<dim3(256, 3), 256, 0, stream>>>(
      xn, wf, f_b, nullptr, feat, nullptr, 192, 512);
  gemm_bt<256, 64, 64, 64, 0><<<dim3(256, 3), 256, 0, stream>>>(
      xn, wv, v_b, nullptr, val, nullptr, 192, 512);

  // 3. cluster centers + normalize
  pool_kernel<<<512, 384, 0, stream>>>(feat, val, cnb, vcb);
  // 4. sim + leaky + top-1
  sim_kernel<<<dim3(4, 512), 256, 0, stream>>>(feat, cnb, alpha, beta, svb, sib);
  // 5. aggregate into centers
  agg_kernel<<<512, 256, 0, stream>>>(val, vcb, svb, sib, agb);
  // 6. dispatch back to tokens (bf16)
  dispatch_kernel<<<2048, 256, 0, stream>>>(svb, sib, agb, o);

  // 7. x1 = x + o @ proj_w^T + proj_b
  gemm_bt<128, 128, 64, 64, 1><<<dim3(512, 4), 256, 0, stream>>>(
      o, wp, proj_b, x, x1, nullptr, 512, 192);

  // 8. h = LN2(x1)  (bf16)
  ln_kernel<<<16384, 256, 0, stream>>>(x1, ln2_g, ln2_b, h);

  // 9/10. MLP, 4 row-chunks of 16384 to bound workspace
  //   fc1: 128x128, grid (128,16)=2048 blocks
  //   fc2: 128x64 (wave 64x32), grid (128,8)=1024 blocks, 16 waves/CU
  for (int c = 0; c < 4; ++c) {
    const short* hA = h + (size_t)c * 16384 * 512;
    gemm_bt<128, 128, 64, 64, 2><<<dim3(128, 16), 256, 0, stream>>>(
        hA, w1, fc1_b, nullptr, nullptr, h1, 2048, 512);
    gemm_bt<128, 64, 64, 32, 1><<<dim3(128, 8), 256, 0, stream>>>(
        h1, w2, fc2_b, x1 + (size_t)c * 16384 * 512,
        out + (size_t)c * 16384 * 512, nullptr, 512, 2048);
  }
  (void)in_sizes; (void)n_in; (void)out_size; (void)ws_size;
}